// Round 1
// 129.418 us; speedup vs baseline: 1.0397x; 1.0397x over previous
//
#include <hip/hip_runtime.h>
#include <hip/hip_bf16.h>

// Gaussian-kernel regression, fused flash-attention style. 3-kernel structure.
// K_prep: 512 one-wave blocks: 256x yt=y@R^T+t GEMM -> KA2C*yt perm + yn hi/lo
//   folded into K=144 slot; 256x V=X[1:] transpose perm.
// K_main (round-6): S via 9 MFMAs (exponent folded), exp2, P redistributed
//   in-register via permlane32_swap (gls LDS round-trip removed, LDS 52->34 KB),
//   split-stage pipelining: yt(T+1) issued after mid-barrier (hides under
//   exp1+PV), V(T+1) issued after end-barrier (hides under next S).
// K_fin : grid (128,4)=512 blocks, sp-loop unrolled x4 -> pipelined 48MB read.
// NOTE (R9, prior session): grid-wide barriers w/ agent-scope fences on gfx950
// = L2 writeback storms, 12x slowdown. Never again.

#define LOG2E 1.44269504088896340736f
#define KNEG (-(1.0f/256.0f)*LOG2E)
#define KA2C (2.0f*(1.0f/256.0f)*LOG2E)

typedef __attribute__((ext_vector_type(4)))  float f32x4;
typedef __attribute__((ext_vector_type(16))) float f32x16;
typedef __attribute__((ext_vector_type(8)))  short bf16x8;

__device__ __forceinline__ unsigned short f2bf(float f) {
  unsigned u = __builtin_bit_cast(unsigned, f);
  u = (u + 0x7fffu + ((u >> 16) & 1u)) >> 16;  // RNE; inputs finite
  return (unsigned short)u;
}
__device__ __forceinline__ unsigned pk2bf(float a, float b) {
  __hip_bfloat162 h = __float22bfloat162_rn(float2{a, b});  // v_cvt_pk_bf16_f32
  unsigned u;
  __builtin_memcpy(&u, &h, 4);
  return u;
}
__device__ __forceinline__ bf16x8 pack8(float4 p0, float4 p1) {
  uint4 u;
  u.x = pk2bf(p0.x, p0.y); u.y = pk2bf(p0.z, p0.w);
  u.z = pk2bf(p1.x, p1.y); u.w = pk2bf(p1.z, p1.w);
  return __builtin_bit_cast(bf16x8, u);
}
__device__ __forceinline__ float fast_exp2(float x) {
#if __has_builtin(__builtin_amdgcn_exp2f)
  return __builtin_amdgcn_exp2f(x);
#else
  return exp2f(x);
#endif
}
__device__ __forceinline__ void gl2lds16(const void* g, void* l) {
  __builtin_amdgcn_global_load_lds((const __attribute__((address_space(1))) unsigned int*)g,
                                   (__attribute__((address_space(3))) unsigned int*)l, 16, 0, 0);
}
__device__ __forceinline__ f32x16 mfma_32x32x16(bf16x8 a, bf16x8 b, f32x16 c) {
  return __builtin_amdgcn_mfma_f32_32x32x16_bf16(a, b, c, 0, 0, 0);
}
// Swap lanes: a' = {a.lo | b.lo-from-low-half}, b' = {a.hi-from-high..};
// i.e. exchanges a's high 32 lanes with b's low 32 lanes (gfx950 permlane32_swap).
__device__ __forceinline__ void pl32swap(unsigned &a, unsigned &b) {
#if __has_builtin(__builtin_amdgcn_permlane32_swap)
  auto r = __builtin_amdgcn_permlane32_swap((int)a, (int)b, false, false);
  a = (unsigned)r[0];
  b = (unsigned)r[1];
#else
  unsigned pa = (unsigned)__shfl_xor((int)a, 32, 64);
  unsigned pb = (unsigned)__shfl_xor((int)b, 32, 64);
  bool hi = (threadIdx.x & 32) != 0;
  unsigned na = hi ? pb : a;
  unsigned nb = hi ? b  : pa;
  a = na; b = nb;
#endif
}

#define T_STRIDE 34816   // per-64j-tile bytes: 2 jc x 9 kc x 1024 (yt) + 16384 (V)
#define V_OFF    18432

// ---------------- K_prep: 512 one-wave blocks ----------------
// task = blockIdx.x. task<256: yt GEMM for 32 rows (tile task>>1, half task&1).
// task>=256: V transpose for 32 X1-rows.
__global__ __launch_bounds__(64) void k_prep(const float* __restrict__ y,
                                             const float* __restrict__ R,
                                             const float* __restrict__ t,
                                             const float* __restrict__ X,
                                             unsigned short* __restrict__ ctp) {
  __shared__ char slice[8704];
  const int task = blockIdx.x;
  const int ln = threadIdx.x;
  const int l = ln & 31, h = ln >> 5;

  if (task < 256) {
    // ---- yt task: rows rw..rw+31; tile T=task>>1, jc half jcw=task&1 ----
    unsigned short* ytt = (unsigned short*)slice;        // [32][132] = 8448 B
    float* ynf = (float*)(slice + 8448);                 // 32 floats
    const int T = task >> 1, jcw = task & 1;
    const int rw = task * 32;
    bf16x8 af[8];
    {
      int row = rw + l; if (row > 8190) row = 8190;
      const float* yr = y + (size_t)row * 128;
#pragma unroll
      for (int kc = 0; kc < 8; ++kc) {
        float4 p0 = *(const float4*)(yr + kc*16 + 8*h);
        float4 p1 = *(const float4*)(yr + kc*16 + 8*h + 4);
        af[kc] = pack8(p0, p1);
      }
    }
    f32x16 ac[4];
#pragma unroll
    for (int cc=0; cc<4; ++cc)
#pragma unroll
      for (int i=0;i<16;++i) ac[cc][i] = 0.f;
#pragma unroll
    for (int cc=0; cc<4; ++cc) {
      const float* Rr = R + (size_t)(cc*32 + l) * 128;   // R^T[k][c] = R[c][k]
#pragma unroll
      for (int kc=0; kc<8; ++kc) {
        float4 p0 = *(const float4*)(Rr + kc*16 + 8*h);
        float4 p1 = *(const float4*)(Rr + kc*16 + 8*h + 4);
        ac[cc] = mfma_32x32x16(af[kc], pack8(p0, p1), ac[cc]);
      }
    }
    // D: lane holds yt[rw + (r&3)+8*(r>>2)+4h][cc*32 + l]
    float tv0 = t[l], tv1 = t[32+l], tv2 = t[64+l], tv3 = t[96+l];
    float v0[16], v1[16], v2[16], v3[16], ssq[16];
#pragma unroll
    for (int r=0;r<16;++r) {
      v0[r]=ac[0][r]+tv0; v1[r]=ac[1][r]+tv1; v2[r]=ac[2][r]+tv2; v3[r]=ac[3][r]+tv3;
      ssq[r] = v0[r]*v0[r] + v1[r]*v1[r] + v2[r]*v2[r] + v3[r]*v3[r];
    }
#pragma unroll
    for (int off=1; off<32; off<<=1)
#pragma unroll
      for (int r=0;r<16;++r) ssq[r] += __shfl_xor(ssq[r], off, 64);
    if (l < 16) {
      int r = l;
      int grow = rw + (r&3) + 8*(r>>2) + 4*h;
      ynf[(r&3) + 8*(r>>2) + 4*h] = (grow >= 8191) ? -1.0e4f : KNEG * ssq[r];
    }
#pragma unroll
    for (int r=0;r<16;++r) {
      int rloc = (r&3) + 8*(r>>2) + 4*h;
      ytt[rloc*132 +   0 + l] = f2bf(KA2C * v0[r]);
      ytt[rloc*132 +  32 + l] = f2bf(KA2C * v1[r]);
      ytt[rloc*132 +  64 + l] = f2bf(KA2C * v2[r]);
      ytt[rloc*132 +  96 + l] = f2bf(KA2C * v3[r]);
    }
    __syncthreads();
    char* base = (char*)ctp + (size_t)T*T_STRIDE;
#pragma unroll
    for (int kc=0;kc<8;++kc) {
      const unsigned short* s = &ytt[l*132 + kc*16 + 8*h];
      uint2 a = *(const uint2*)(s);
      uint2 b = *(const uint2*)(s + 4);
      uint4 o; o.x=a.x; o.y=a.y; o.z=b.x; o.w=b.y;
      *(uint4*)(base + (jcw*9 + kc)*1024 + ln*16) = o;
    }
    {  // kc=8 slot: k=128 -> yn_hi, k=129 -> yn_lo (h=0 lanes only)
      float yn = ynf[l];
      unsigned short hi = f2bf(yn);
      float hif = __builtin_bit_cast(float, (unsigned)hi << 16);
      unsigned short lo = f2bf(yn - hif);
      uint4 o; o.x = (h == 0) ? ((unsigned)hi | ((unsigned)lo << 16)) : 0u;
      o.y = 0u; o.z = 0u; o.w = 0u;
      *(uint4*)(base + (jcw*9 + 8)*1024 + ln*16) = o;
    }
  } else {
    // ---- V task: 32 X1-rows; tile T2=(task-256)>>1, half=(task-256)&1 ----
    unsigned short* xs = (unsigned short*)slice;         // [32][136] bf16 = 8704 B
    const int tv_ = task - 256;
    const int T2 = tv_ >> 1, half = tv_ & 1;
    const int xr0 = T2*64 + half*32 + 1;
    {
      int rl = ln >> 1, ch2 = ln & 1;
      int row = xr0 + rl; if (row > 8191) row = 8191;   // pad j has g=0
      const float* src = X + (size_t)row*128 + ch2*64;
      unsigned short* dst = xs + rl*136 + ch2*64;
#pragma unroll
      for (int i=0;i<8;++i) {
        float4 p0 = *(const float4*)(src + i*8);
        float4 p1 = *(const float4*)(src + i*8 + 4);
        uint4 w;
        w.x = pk2bf(p0.x, p0.y); w.y = pk2bf(p0.z, p0.w);
        w.z = pk2bf(p1.x, p1.y); w.w = pk2bf(p1.z, p1.w);
        *(uint4*)(dst + i*8) = w;
      }
    }
    __syncthreads();
    char* base = (char*)ctp + (size_t)T2*T_STRIDE + V_OFF;
#pragma unroll
    for (int ch=0; ch<8; ++ch) {
      int jcl = ch >> 2, cc = ch & 3;
      int lr0 = jcl*16 + 8*h;
      int c = cc*32 + l;
      uint4 o;
      o.x = (unsigned)xs[(lr0+0)*136 + c] | ((unsigned)xs[(lr0+1)*136 + c] << 16);
      o.y = (unsigned)xs[(lr0+2)*136 + c] | ((unsigned)xs[(lr0+3)*136 + c] << 16);
      o.z = (unsigned)xs[(lr0+4)*136 + c] | ((unsigned)xs[(lr0+5)*136 + c] << 16);
      o.w = (unsigned)xs[(lr0+6)*136 + c] | ((unsigned)xs[(lr0+7)*136 + c] << 16);
      int jc16 = half*2 + jcl;
      *(uint4*)(base + (jc16*4 + cc)*1024 + ln*16) = o;
    }
  }
}

// ---------------- K_main (round-6: permlane P + split-stage pipeline) --------
// grid (64, js); block 256 = 4 waves x 32 query rows (BM=128); 3 blocks/CU.
// Per tile: S0,S1 (18 MFMA) ; exp0 ; BAR ; issue yt(T+1) ; exp1 + PV (16 MFMA,
// P via permlane32_swap) ; BAR ; issue V(T+1).  Each stage drains at the NEXT
// barrier's vmcnt(0), hidden under the intervening compute phase.
__global__ __launch_bounds__(256, 3) void k_main(
    const float* __restrict__ X,
    const unsigned short* __restrict__ ctp,
    float* __restrict__ accp,
    float* __restrict__ rsp,
    int js) {
  __shared__ unsigned short stg[T_STRIDE/2];   // 34816 B: yt(2jc x 9kc) + V
  const int tid = threadIdx.x;
  const int wv = tid >> 6, ln = tid & 63;
  const int l = ln & 31, h = ln >> 5;
  const int row = blockIdx.x*128 + wv*32 + l;  // query row, always < 8192

  bf16x8 qf[9];  // Q as B-operand: x[row][k], plus k=128,129 -> 1,1 (h=0)
  {
    const float* xr = X + (size_t)row * 128;
#pragma unroll
    for (int kc=0;kc<8;++kc) {
      float4 p0 = *(const float4*)(xr + kc*16 + 8*h);
      float4 p1 = *(const float4*)(xr + kc*16 + 8*h + 4);
      qf[kc] = pack8(p0, p1);
    }
    uint4 o; o.x = (h == 0) ? 0x3F803F80u : 0u; o.y = 0u; o.z = 0u; o.w = 0u;
    qf[8] = __builtin_bit_cast(bf16x8, o);
  }
  f32x16 acc[4];
#pragma unroll
  for (int cc=0;cc<4;++cc)
#pragma unroll
    for (int i=0;i<16;++i) acc[cc][i]=0.f;
  float rs = 0.f;
  const int sp = blockIdx.y;
  const int Tbeg = (sp * 128) / js;
  const int Tend = ((sp + 1) * 128) / js;

  // softmax-exp of one S quadrant -> packed bf16 pair words
  auto dosm = [&](const f32x16& sa, unsigned wx[4], unsigned wy[4]) {
#pragma unroll
    for (int rg=0; rg<4; ++rg) {
      float g0 = fast_exp2(sa[rg*4+0]);
      float g1 = fast_exp2(sa[rg*4+1]);
      float g2 = fast_exp2(sa[rg*4+2]);
      float g3 = fast_exp2(sa[rg*4+3]);
      rs += (g0+g1) + (g2+g3);
      wx[rg] = pk2bf(g0, g1);
      wy[rg] = pk2bf(g2, g3);
    }
  };
  // PV for one jc: lane (h',l) needs P[j=jc16*16+8h'+e][m=l]; source word for
  // e0..3 is W[2jj+h'] from the h=0 half, e4..7 from the h=1 half -> one
  // permlane32_swap per (x,y) word pair yields (word0,word2)/(word1,word3).
  auto dopv = [&](int jcb, unsigned wx[4], unsigned wy[4]) {
#pragma unroll
    for (int jj=0; jj<2; ++jj) {
      unsigned ax = wx[2*jj], bx = wx[2*jj+1];
      unsigned ay = wy[2*jj], by = wy[2*jj+1];
      pl32swap(ax, bx);
      pl32swap(ay, by);
      uint4 gv; gv.x = ax; gv.y = ay; gv.z = bx; gv.w = by;
      bf16x8 pb = __builtin_bit_cast(bf16x8, gv);
#pragma unroll
      for (int cc=0;cc<4;++cc) {
        bf16x8 a2 = *(const bf16x8*)((const char*)stg + V_OFF + ((jcb+jj)*4+cc)*1024 + ln*16);
        acc[cc] = mfma_32x32x16(a2, pb, acc[cc]);
      }
    }
  };

  // prologue: stage full tile Tbeg (34 chunks of 1 KB)
  {
    const char* cb = (const char*)ctp + (size_t)Tbeg*T_STRIDE;
#pragma unroll
    for (int i=0;i<9;++i) {
      int c = wv + 4*i;
      if (c < 34) gl2lds16(cb + c*1024 + ln*16, (char*)stg + c*1024);
    }
  }
  __syncthreads();  // drain prologue stage

  for (int T = Tbeg; T < Tend; ++T) {
    const bool pf = (T+1 < Tend);
    const char* nb = (const char*)ctp + (size_t)(T+1)*T_STRIDE;

    // ---- S phase: 18 MFMAs reading all yt chunks ----
    f32x16 sa0, sa1;
#pragma unroll
    for (int i=0;i<16;++i) { sa0[i]=0.f; sa1[i]=0.f; }
#pragma unroll
    for (int kc=0;kc<9;++kc) {
      bf16x8 a0 = *(const bf16x8*)((const char*)stg + kc*1024 + ln*16);
      sa0 = mfma_32x32x16(a0, qf[kc], sa0);
    }
#pragma unroll
    for (int kc=0;kc<9;++kc) {
      bf16x8 a1 = *(const bf16x8*)((const char*)stg + (9+kc)*1024 + ln*16);
      sa1 = mfma_32x32x16(a1, qf[kc], sa1);
    }
    unsigned wx0[4], wy0[4], wx1[4], wy1[4];
    dosm(sa0, wx0, wy0);   // before barrier: sa0 dead across it (reg pressure)

    __syncthreads();       // all waves done reading yt region
    if (pf) {              // prefetch next yt (chunks 0..17); drains at end BAR
#pragma unroll
      for (int i=0;i<5;++i) {
        int c = wv + 4*i;
        if (c < 18) gl2lds16(nb + c*1024 + ln*16, (char*)stg + c*1024);
      }
    }
    dosm(sa1, wx1, wy1);
    dopv(0, wx0, wy0);     // PV jc=0: 8 MFMAs
    dopv(2, wx1, wy1);     // PV jc=1: 8 MFMAs

    __syncthreads();       // all V reads done; vmcnt(0) -> next yt landed
    if (pf) {              // stage next V (chunks 18..33); drains at mid BAR
#pragma unroll
      for (int i=0;i<4;++i) {
        int c = 18 + wv + 4*i;
        gl2lds16(nb + c*1024 + ln*16, (char*)stg + c*1024);
      }
    }
  }
  rs += __shfl_xor(rs, 32, 64);
  if (h == 0) rsp[(size_t)sp*8192 + row] = rs;
  // acc^T: lane holds out^T[c = cc*32+(r&3)+8(r>>2)+4h][m = row]; store [sp][c][row]
#pragma unroll
  for (int cc=0;cc<4;++cc)
#pragma unroll
    for (int r=0;r<16;++r) {
      int c = cc*32 + (r&3) + 8*(r>>2) + 4*h;
      accp[((size_t)sp*128 + c)*8192 + row] = acc[cc][r];
    }
}

// ---------------- K_fin: pipelined split-reduce + normalize + transpose --------
// grid (128, 4) = 512 blocks (2/CU). Block: 64 rows x 32 cols.
// Thread: rows rq*4..+3 (r-contig float4), cols c0 + cg*2..+1. sp-loop unroll 4
// -> 8 float4 loads in flight per thread.
__global__ __launch_bounds__(256) void k_fin(const float* __restrict__ accp,
                                             const float* __restrict__ rsp,
                                             float* __restrict__ out,
                                             int js) {
  __shared__ float tr[64*36];   // stride 36 floats (144 B, 16B-aligned rows)
  __shared__ float rinv[64];
  const int tid = threadIdx.x;
  const int r0 = blockIdx.x * 64;
  const int c0 = blockIdx.y * 32;
  if (tid < 64) {
    float s = 0.f;
    for (int sp=0; sp<js; ++sp) s += rsp[(size_t)sp*8192 + r0 + tid];
    rinv[tid] = 1.f / s;
  }
  const int rq = tid & 15, cg = tid >> 4;   // rows rq*4..+3, cols c0+cg*2..+1
  float v[2][4];
#pragma unroll
  for (int cc=0;cc<2;++cc)
#pragma unroll
    for (int k=0;k<4;++k) v[cc][k]=0.f;
#pragma unroll 4
  for (int sp=0; sp<js; ++sp) {
    const float* base = accp + ((size_t)sp*128 + c0 + cg*2)*8192 + r0 + rq*4;
    float4 p0 = *(const float4*)(base);
    float4 p1 = *(const float4*)(base + 8192);
    v[0][0]+=p0.x; v[0][1]+=p0.y; v[0][2]+=p0.z; v[0][3]+=p0.w;
    v[1][0]+=p1.x; v[1][1]+=p1.y; v[1][2]+=p1.z; v[1][3]+=p1.w;
  }
  __syncthreads();
#pragma unroll
  for (int cc=0;cc<2;++cc)
#pragma unroll
    for (int k=0;k<4;++k)
      tr[(rq*4+k)*36 + cg*2+cc] = v[cc][k] * rinv[rq*4+k];
  __syncthreads();
  {
    int r = tid >> 2, q = tid & 3;   // 64 rows x 4 col-groups of 8
    int grow = r0 + r;
    if (grow < 8191) {
      float* dst = out + (size_t)grow*128 + c0 + q*8;
      const float* s2 = &tr[r*36 + q*8];
      *(float4*)(dst)     = *(const float4*)(s2);
      *(float4*)(dst + 4) = *(const float4*)(s2 + 4);
    }
  }
}

extern "C" void kernel_launch(void* const* d_in, const int* in_sizes, int n_in,
                              void* d_out, int out_size, void* d_ws, size_t ws_size,
                              hipStream_t stream) {
  const float* X = (const float*)d_in[0];
  const float* y = (const float*)d_in[1];
  // d_in[2] = y_next (unused by reference)
  const float* R = (const float*)d_in[3];
  const float* t = (const float*)d_in[4];
  float* out = (float*)d_out;
  char* ws = (char*)d_ws;

  unsigned short* ctp = (unsigned short*)ws;                 // 128 * 34816 = 4.456 MB
  size_t rspoff = (size_t)128 * T_STRIDE;
  float* rsp  = (float*)(ws + rspoff);                       // js*32 KB
  size_t accoff = rspoff + 512*1024;
  float* accp = (float*)(ws + accoff);                       // js * 4 MB

  int js = 12;  // 64 x 12 = 768 blocks = exactly 3 blocks/CU
  while (js > 1 && accoff + (size_t)js*128*8192*4 > ws_size) js >>= 1;

  k_prep<<<dim3(512), dim3(64), 0, stream>>>(y, R, t, X, ctp);
  k_main<<<dim3(64, js), dim3(256), 0, stream>>>(X, ctp, accp, rsp, js);
  k_fin<<<dim3(128, 4), dim3(256), 0, stream>>>(accp, rsp, out, js);
}